// Round 1
// baseline (249.906 us; speedup 1.0000x reference)
//
#include <hip/hip_runtime.h>
#include <stdint.h>

#define HW 3136
#define IMGW 56

static __device__ __forceinline__ int dot4i8(int a, int b, int c) {
#if __has_builtin(__builtin_amdgcn_sdot4)
  return __builtin_amdgcn_sdot4(a, b, c, false);
#else
  c += (int)(int8_t)(a      ) * (int)(int8_t)(b      );
  c += (int)(int8_t)(a >>  8) * (int)(int8_t)(b >>  8);
  c += (int)(int8_t)(a >> 16) * (int)(int8_t)(b >> 16);
  c += (int)(int8_t)(a >> 24) * (int)(int8_t)(b >> 24);
  return c;
#endif
}

// BN: round((alpha*acc + off) * 2^-10), clamp to [-128,127]. Exact f32 ops,
// no contraction (matches numpy mul/add/round-half-even chain bit-exactly).
static __device__ __forceinline__ float bnq(float alpha, float off, int acc) {
  float t = __fmul_rn(alpha, (float)acc);
  t = __fadd_rn(t, off);
  t = __fmul_rn(t, 0x1p-10f);
  float r = rintf(t);
  return fminf(fmaxf(r, -128.0f), 127.0f);
}

// ---------------- prep: pack weights + fold BN constants ----------------
__global__ void prep_kernel(
    const int* __restrict__ s1, const int* __restrict__ m1,
    const float* __restrict__ a1, const float* __restrict__ b1, const int* __restrict__ q1,
    const int* __restrict__ s2, const int* __restrict__ m2,
    const float* __restrict__ a2, const float* __restrict__ b2, const int* __restrict__ q2,
    const int* __restrict__ s3, const int* __restrict__ m3,
    const float* __restrict__ a3, const float* __restrict__ b3, const int* __restrict__ q3,
    int* __restrict__ w1p, int* __restrict__ w2p, int* __restrict__ w3p,
    float* __restrict__ a1p, float* __restrict__ o1p,
    float* __restrict__ a2p, float* __restrict__ o2p,
    float* __restrict__ a3p, float* __restrict__ o3p)
{
  int t = blockIdx.x * blockDim.x + threadIdx.x;
  int nthr = gridDim.x * blockDim.x;

  // w1p[cg*64 + co] packs input channels cg*4..cg*4+3 for output co (conv1: 64x256)
  for (int i = t; i < 64 * 64; i += nthr) {
    int cg = i >> 6, co = i & 63;
    int p = 0;
    for (int j = 0; j < 4; ++j) {
      int ci = cg * 4 + j;
      int idx = co * 256 + ci;
      int w = m1[idx] * (1 << s1[idx]);
      p |= (w & 0xFF) << (8 * j);
    }
    w1p[i] = p;
  }
  // w2p[(tap*16+cg)*64 + co], tap = ky*3+kx (conv2: 64x64x3x3)
  for (int i = t; i < 9 * 16 * 64; i += nthr) {
    int co = i & 63;
    int rest = i >> 6;
    int cg = rest & 15;
    int tap = rest >> 4;
    int ky = tap / 3, kx = tap % 3;
    int p = 0;
    for (int j = 0; j < 4; ++j) {
      int ci = cg * 4 + j;
      int idx = ((co * 64 + ci) * 3 + ky) * 3 + kx;
      int w = m2[idx] * (1 << s2[idx]);
      p |= (w & 0xFF) << (8 * j);
    }
    w2p[i] = p;
  }
  // w3p[(co4*16+cg)*4 + j]: output channel co4*4+j, input group cg (conv3: 256x64)
  for (int i = t; i < 64 * 16 * 4; i += nthr) {
    int j = i & 3;
    int cg = (i >> 2) & 15;
    int co4 = i >> 6;
    int co = co4 * 4 + j;
    int p = 0;
    for (int jj = 0; jj < 4; ++jj) {
      int ci = cg * 4 + jj;
      int idx = co * 64 + ci;
      int w = m3[idx] * (1 << s3[idx]);
      p |= (w & 0xFF) << (8 * jj);
    }
    w3p[i] = p;
  }
  for (int i = t; i < 64; i += nthr) {
    a1p[i] = a1[i];
    o1p[i] = __fmul_rn(b1[i], exp2f((float)q1[i] + 10.0f));
    a2p[i] = a2[i];
    o2p[i] = __fmul_rn(b2[i], exp2f((float)q2[i] + 10.0f));
  }
  for (int i = t; i < 256; i += nthr) {
    a3p[i] = a3[i];
    o3p[i] = __fmul_rn(b3[i], exp2f((float)q3[i] + 10.0f));
  }
}

// ---------------- k1: conv1 1x1 (256->64) + BN + relu ----------------
// Also emits packed-int8 copy of x for the residual in k3.
__global__ __launch_bounds__(256) void k1_conv1(
    const float* __restrict__ x,
    const int* __restrict__ w1p,
    const float* __restrict__ a1p, const float* __restrict__ o1p,
    int* __restrict__ y1p, int* __restrict__ x8p, int writeX8)
{
  int g = blockIdx.x * 256 + threadIdx.x;
  int n = g / HW;
  int pos = g - n * HW;
  const float* xb = x + (size_t)n * 256 * HW + pos;

  int acc[64];
#pragma unroll
  for (int i = 0; i < 64; ++i) acc[i] = 0;

  for (int cg = 0; cg < 64; ++cg) {
    float f0 = xb[(cg * 4 + 0) * HW];
    float f1 = xb[(cg * 4 + 1) * HW];
    float f2 = xb[(cg * 4 + 2) * HW];
    float f3 = xb[(cg * 4 + 3) * HW];
    int xv = ((int)f0 & 0xFF) | (((int)f1 & 0xFF) << 8) |
             (((int)f2 & 0xFF) << 16) | (((int)f3 & 0xFF) << 24);
    if (writeX8) x8p[((size_t)n * 64 + cg) * HW + pos] = xv;
    const int4* wr = (const int4*)(w1p + cg * 64);
#pragma unroll
    for (int co4 = 0; co4 < 16; ++co4) {
      int4 wv = wr[co4];
      acc[co4 * 4 + 0] = dot4i8(xv, wv.x, acc[co4 * 4 + 0]);
      acc[co4 * 4 + 1] = dot4i8(xv, wv.y, acc[co4 * 4 + 1]);
      acc[co4 * 4 + 2] = dot4i8(xv, wv.z, acc[co4 * 4 + 2]);
      acc[co4 * 4 + 3] = dot4i8(xv, wv.w, acc[co4 * 4 + 3]);
    }
  }

#pragma unroll
  for (int co4 = 0; co4 < 16; ++co4) {
    int p = 0;
#pragma unroll
    for (int j = 0; j < 4; ++j) {
      int co = co4 * 4 + j;
      float r = bnq(a1p[co], o1p[co], acc[co]);
      int v = (int)r;
      if (v < 0) v = 0;  // relu
      p |= (v & 0xFF) << (8 * j);
    }
    y1p[((size_t)n * 16 + co4) * HW + pos] = p;
  }
}

// ---------------- k2: conv2 3x3 (64->64, pad 1) + BN + relu ----------------
__global__ __launch_bounds__(256) void k2_conv2(
    const int* __restrict__ y1p,
    const int* __restrict__ w2p,
    const float* __restrict__ a2p, const float* __restrict__ o2p,
    int* __restrict__ y2p)
{
  int g = blockIdx.x * 256 + threadIdx.x;
  int n = g / HW;
  int pos = g - n * HW;
  int h = pos / IMGW;
  int w = pos - h * IMGW;

  int acc[64];
#pragma unroll
  for (int i = 0; i < 64; ++i) acc[i] = 0;

  const int* yb = y1p + (size_t)n * 16 * HW;

  for (int ky = 0; ky < 3; ++ky) {
    int hh = h + ky - 1;
    bool okh = (unsigned)hh < 56u;
    for (int kx = 0; kx < 3; ++kx) {
      int ww = w + kx - 1;
      bool ok = okh && ((unsigned)ww < 56u);
      int pos2 = hh * IMGW + ww;
      int tap = ky * 3 + kx;
      const int* wbase = w2p + tap * 16 * 64;
      for (int cg = 0; cg < 16; ++cg) {
        int xv = ok ? yb[cg * HW + pos2] : 0;
        const int4* wr = (const int4*)(wbase + cg * 64);
#pragma unroll
        for (int co4 = 0; co4 < 16; ++co4) {
          int4 wv = wr[co4];
          acc[co4 * 4 + 0] = dot4i8(xv, wv.x, acc[co4 * 4 + 0]);
          acc[co4 * 4 + 1] = dot4i8(xv, wv.y, acc[co4 * 4 + 1]);
          acc[co4 * 4 + 2] = dot4i8(xv, wv.z, acc[co4 * 4 + 2]);
          acc[co4 * 4 + 3] = dot4i8(xv, wv.w, acc[co4 * 4 + 3]);
        }
      }
    }
  }

#pragma unroll
  for (int co4 = 0; co4 < 16; ++co4) {
    int p = 0;
#pragma unroll
    for (int j = 0; j < 4; ++j) {
      int co = co4 * 4 + j;
      float r = bnq(a2p[co], o2p[co], acc[co]);
      int v = (int)r;
      if (v < 0) v = 0;
      p |= (v & 0xFF) << (8 * j);
    }
    y2p[((size_t)n * 16 + co4) * HW + pos] = p;
  }
}

// ---------------- k3: conv3 1x1 (64->256) + BN + residual + relu ----------------
__global__ __launch_bounds__(256) void k3_conv3(
    const int* __restrict__ y2p,
    const int* __restrict__ w3p,
    const float* __restrict__ a3p, const float* __restrict__ o3p,
    const int* __restrict__ x8p, const float* __restrict__ x, int useX8,
    float* __restrict__ out)
{
  int g = blockIdx.x * 256 + threadIdx.x;
  int n = g / HW;
  int pos = g - n * HW;

  int xp[16];
#pragma unroll
  for (int cg = 0; cg < 16; ++cg)
    xp[cg] = y2p[((size_t)n * 16 + cg) * HW + pos];

  for (int co4 = 0; co4 < 64; ++co4) {
    const int4* wr = (const int4*)(w3p + co4 * 64);
    int ac0 = 0, ac1 = 0, ac2 = 0, ac3 = 0;
#pragma unroll
    for (int cg = 0; cg < 16; ++cg) {
      int4 wv = wr[cg];
      ac0 = dot4i8(xp[cg], wv.x, ac0);
      ac1 = dot4i8(xp[cg], wv.y, ac1);
      ac2 = dot4i8(xp[cg], wv.z, ac2);
      ac3 = dot4i8(xp[cg], wv.w, ac3);
    }

    int id0, id1, id2, id3;
    if (useX8) {
      int ip = x8p[((size_t)n * 64 + co4) * HW + pos];
      id0 = (int)(int8_t)(ip);
      id1 = (int)(int8_t)(ip >> 8);
      id2 = (int)(int8_t)(ip >> 16);
      id3 = (int)(int8_t)(ip >> 24);
    } else {
      const float* xb = x + ((size_t)n * 256 + co4 * 4) * HW + pos;
      id0 = (int)xb[0];
      id1 = (int)xb[HW];
      id2 = (int)xb[2 * HW];
      id3 = (int)xb[3 * HW];
    }

    float* ob = out + ((size_t)n * 256 + (size_t)co4 * 4) * HW + pos;
    int accs[4] = {ac0, ac1, ac2, ac3};
    int ids[4] = {id0, id1, id2, id3};
#pragma unroll
    for (int j = 0; j < 4; ++j) {
      int co = co4 * 4 + j;
      float r = bnq(a3p[co], o3p[co], accs[j]);
      int v = (int)r + ids[j];
      v = v > 127 ? 127 : v;
      v = v < 0 ? 0 : v;  // clamp(-128,..) then relu => max(0, min(127, .))
      ob[(size_t)j * HW] = (float)v;
    }
  }
}

extern "C" void kernel_launch(void* const* d_in, const int* in_sizes, int n_in,
                              void* d_out, int out_size, void* d_ws, size_t ws_size,
                              hipStream_t stream) {
  const float* x  = (const float*)d_in[0];
  const int*   s1 = (const int*)d_in[1];
  const int*   m1 = (const int*)d_in[2];
  const float* a1 = (const float*)d_in[3];
  const float* b1 = (const float*)d_in[4];
  const int*   q1 = (const int*)d_in[5];
  const int*   s2 = (const int*)d_in[6];
  const int*   m2 = (const int*)d_in[7];
  const float* a2 = (const float*)d_in[8];
  const float* b2 = (const float*)d_in[9];
  const int*   q2 = (const int*)d_in[10];
  const int*   s3 = (const int*)d_in[11];
  const int*   m3 = (const int*)d_in[12];
  const float* a3 = (const float*)d_in[13];
  const float* b3 = (const float*)d_in[14];
  const int*   q3 = (const int*)d_in[15];

  char* ws = (char*)d_ws;
  int* w1p = (int*)(ws + 0);        // 16384 B
  int* w2p = (int*)(ws + 16384);    // 36864 B
  int* w3p = (int*)(ws + 53248);    // 16384 B
  float* a1p = (float*)(ws + 69632);
  float* o1p = (float*)(ws + 69888);
  float* a2p = (float*)(ws + 70144);
  float* o2p = (float*)(ws + 70400);
  float* a3p = (float*)(ws + 70656);
  float* o3p = (float*)(ws + 71680);
  int* y1p = (int*)(ws + 73728);                       // 6,422,528 B
  int* y2p = (int*)(ws + 73728 + 6422528);             // 6,422,528 B
  int* x8p = (int*)(ws + 73728 + 2 * 6422528);         // 25,690,112 B
  size_t need_x8 = 73728 + 2 * (size_t)6422528 + 25690112;
  int useX8 = (ws_size >= need_x8) ? 1 : 0;

  prep_kernel<<<64, 256, 0, stream>>>(s1, m1, a1, b1, q1,
                                      s2, m2, a2, b2, q2,
                                      s3, m3, a3, b3, q3,
                                      w1p, w2p, w3p,
                                      a1p, o1p, a2p, o2p, a3p, o3p);

  const int grid = (32 * HW) / 256;  // 392
  k1_conv1<<<grid, 256, 0, stream>>>(x, w1p, a1p, o1p, y1p, x8p, useX8);
  k2_conv2<<<grid, 256, 0, stream>>>(y1p, w2p, a2p, o2p, y2p);
  k3_conv3<<<grid, 256, 0, stream>>>(y2p, w3p, a3p, o3p, x8p, x, useX8,
                                     (float*)d_out);
}